// Round 1
// baseline (355.969 us; speedup 1.0000x reference)
//
#include <hip/hip_runtime.h>
#include <hip/hip_bf16.h>

#define D_MODEL 1024
#define N_HEADS 16
#define HEAD_DIM 64
#define SEQ 2048
#define BATCH 2
#define INNER_DIM 4096
#define ROWS (BATCH*SEQ)   // 4096

using f32x4  = __attribute__((ext_vector_type(4))) float;
using bf16x8 = __attribute__((ext_vector_type(8))) short;   // 8 bf16 raw bits

__device__ __forceinline__ void gl_lds16(const void* g, void* l) {
  __builtin_amdgcn_global_load_lds(
      (const __attribute__((address_space(1))) void*)g,
      (__attribute__((address_space(3))) void*)l, 16, 0, 0);
}

__device__ __forceinline__ float bf2f(unsigned short u) {
  union { unsigned int i; float f; } v; v.i = ((unsigned int)u) << 16; return v.f;
}
__device__ __forceinline__ unsigned short f2bf(float f) {
  union { float f; unsigned int i; } v; v.f = f;
  unsigned int x = v.i;
  return (unsigned short)((x + 0x7fffu + ((x >> 16) & 1u)) >> 16);  // RTNE
}

__device__ __forceinline__ float gelu_tanh(float x) {
  float x3 = x * x * x;
  float z = 0.7978845608028654f * (x + 0.044715f * x3);
  z = fminf(z, 15.0f);                       // tanh(15)==1, avoid exp overflow
  float e = __expf(2.0f * z);
  float th = (e - 1.0f) / (e + 1.0f);
  return 0.5f * x * (1.0f + th);
}

// ---------------- weight convert + transpose: in[K][N] f32 -> out[N][K] bf16 ----
__global__ void transpose_convert(const float* __restrict__ in,
                                  unsigned short* __restrict__ out,
                                  int K, int N) {
  __shared__ float tile[32][33];
  int n0 = blockIdx.x * 32, k0 = blockIdx.y * 32;
  int tx = threadIdx.x, ty = threadIdx.y;   // 32 x 8
#pragma unroll
  for (int i = 0; i < 4; i++)
    tile[ty + i * 8][tx] = in[(size_t)(k0 + ty + i * 8) * N + n0 + tx];
  __syncthreads();
#pragma unroll
  for (int i = 0; i < 4; i++)
    out[(size_t)(n0 + ty + i * 8) * K + k0 + tx] = f2bf(tile[tx][ty + i * 8]);
}

// ---------------- LayerNorm + adaLN modulation -> bf16 ------------------------
template<int SH_IDX, int SC_IDX>
__global__ void ln_mod_kernel(const float* __restrict__ x,
                              const float* __restrict__ lw,
                              const float* __restrict__ lb,
                              const float* __restrict__ sst,
                              const float* __restrict__ temb,
                              unsigned short* __restrict__ out) {
  int row = blockIdx.x;            // 0..4095
  int b = row >> 11;               // row / 2048
  int t = threadIdx.x;             // 256
  const float* xr = x + (size_t)row * D_MODEL;
  float4 v = ((const float4*)xr)[t];
  float s = v.x + v.y + v.z + v.w;
  float s2 = v.x * v.x + v.y * v.y + v.z * v.z + v.w * v.w;
#pragma unroll
  for (int o = 1; o < 64; o <<= 1) { s += __shfl_xor(s, o); s2 += __shfl_xor(s2, o); }
  __shared__ float red[8];
  int wid = t >> 6, lane = t & 63;
  if (lane == 0) { red[wid] = s; red[4 + wid] = s2; }
  __syncthreads();
  s = red[0] + red[1] + red[2] + red[3];
  s2 = red[4] + red[5] + red[6] + red[7];
  float mu = s * (1.0f / D_MODEL);
  float var = s2 * (1.0f / D_MODEL) - mu * mu;
  float rs = rsqrtf(var + 1e-5f);
  int d0 = t * 4;
  float xv[4] = { v.x, v.y, v.z, v.w };
  ushort4 ov;
  unsigned short* po = (unsigned short*)&ov;
#pragma unroll
  for (int j = 0; j < 4; j++) {
    int d = d0 + j;
    float ln = (xv[j] - mu) * rs * lw[d] + lb[d];
    float sc = sst[SC_IDX * D_MODEL + d] + temb[b * 6 * D_MODEL + SC_IDX * D_MODEL + d];
    float sh = sst[SH_IDX * D_MODEL + d] + temb[b * 6 * D_MODEL + SH_IDX * D_MODEL + d];
    po[j] = f2bf(ln * (1.0f + sc) + sh);
  }
  *((ushort4*)(out + (size_t)row * D_MODEL + d0)) = ov;
}

// ---------------- RoPE in place on q,k halves of qkv --------------------------
__global__ void rope_kernel(unsigned short* __restrict__ qkv,
                            const float* __restrict__ cosb,
                            const float* __restrict__ sinb) {
  int t = blockIdx.x * blockDim.x + threadIdx.x;   // ROWS*1024 pairs (q and k)
  int row = t >> 10;
  int rem = t & 1023;
  int qk = rem >> 9;
  int rem2 = rem & 511;
  int hh = rem2 >> 5;
  int i = rem2 & 31;
  int s = row & (SEQ - 1);
  unsigned int* p = (unsigned int*)(qkv + (size_t)row * 3072 + qk * 1024 + hh * 64 + 2 * i);
  unsigned int pv = *p;
  float xe = bf2f((unsigned short)(pv & 0xffff));
  float xo = bf2f((unsigned short)(pv >> 16));
  float c = cosb[s * 32 + i], sn = sinb[s * 32 + i];
  float oe = xe * c - xo * sn;
  float oo = xe * sn + xo * c;
  *p = (((unsigned int)f2bf(oo)) << 16) | (unsigned int)f2bf(oe);
}

// ---------------- GEMM: C[M,N] = A[M,K] @ Bt[N,K]^T + bias, fused epilogues ---
enum { EPI_BF16 = 0, EPI_RES = 1, EPI_GELU = 2, EPI_FINAL = 3 };

template<int EPI>
__global__ __launch_bounds__(256, 2)
void gemm_kernel(const unsigned short* __restrict__ A,
                 const unsigned short* __restrict__ Bt,
                 const float* __restrict__ bias,
                 void* __restrict__ Cout,
                 int M, int N, int K,
                 const float* __restrict__ sst,
                 const float* __restrict__ temb,
                 int g_idx,
                 const float* __restrict__ res) {
  __shared__ unsigned short Alds[128 * 32];
  __shared__ unsigned short Blds[128 * 32];
  const int t = threadIdx.x;
  const int w = t >> 6, l = t & 63;
  const int lg = l >> 4, ll = l & 15;
  const int wm = w >> 1, wn = w & 1;
  const int m0 = blockIdx.y * 128, n0 = blockIdx.x * 128;

  f32x4 acc[4][4] = {};

  for (int k0 = 0; k0 < K; k0 += 32) {
#pragma unroll
    for (int i = 0; i < 2; i++) {
      int c = i * 256 + t;
      int row = c >> 2, ch = c & 3;
      gl_lds16(A  + (size_t)(m0 + row) * K + k0 + ch * 8, (char*)Alds + c * 16);
      gl_lds16(Bt + (size_t)(n0 + row) * K + k0 + ch * 8, (char*)Blds + c * 16);
    }
    __syncthreads();
    bf16x8 af[4], bfr[4];
#pragma unroll
    for (int mf = 0; mf < 4; mf++)
      af[mf] = *(const bf16x8*)((const char*)Alds + (wm * 64 + mf * 16 + ll) * 64 + lg * 16);
#pragma unroll
    for (int nf = 0; nf < 4; nf++)
      bfr[nf] = *(const bf16x8*)((const char*)Blds + (wn * 64 + nf * 16 + ll) * 64 + lg * 16);
#pragma unroll
    for (int mf = 0; mf < 4; mf++)
#pragma unroll
      for (int nf = 0; nf < 4; nf++)
        acc[mf][nf] = __builtin_amdgcn_mfma_f32_16x16x32_bf16(af[mf], bfr[nf], acc[mf][nf], 0, 0, 0);
    __syncthreads();
  }

#pragma unroll
  for (int mf = 0; mf < 4; mf++) {
#pragma unroll
    for (int nf = 0; nf < 4; nf++) {
      int col = n0 + wn * 64 + nf * 16 + ll;
      float bv = bias[col];
#pragma unroll
      for (int r = 0; r < 4; r++) {
        int row = m0 + wm * 64 + mf * 16 + lg * 4 + r;
        float v = acc[mf][nf][r] + bv;
        if constexpr (EPI == EPI_BF16) {
          ((unsigned short*)Cout)[(size_t)row * N + col] = f2bf(v);
        } else if constexpr (EPI == EPI_GELU) {
          ((unsigned short*)Cout)[(size_t)row * N + col] = f2bf(gelu_tanh(v));
        } else {
          int bb = row >> 11;
          float g = sst[g_idx * D_MODEL + col] + temb[bb * 6 * D_MODEL + g_idx * D_MODEL + col];
          ((float*)Cout)[(size_t)row * N + col] = v * g + res[(size_t)row * N + col];
        }
      }
    }
  }
}

// ---------------- Flash attention (causal), 128-row Q block, 64-key tiles -----
__global__ __launch_bounds__(256, 2)
void attn_kernel(const unsigned short* __restrict__ qkv,
                 unsigned short* __restrict__ attn_o) {
  __shared__ unsigned short Klds[64 * 64];      // [key][d], 16B-chunk XOR swizzled
  __shared__ unsigned short Vlds[64 * 72];      // [d][key], rows padded to 72
  __shared__ unsigned short Plds[4][32 * 72];   // per wave [q][key], rows padded to 72

  const int b = blockIdx.y >> 4;
  const int h = blockIdx.y & 15;
  const int q0 = blockIdx.x * 128;
  const int t = threadIdx.x;
  const int w = t >> 6, l = t & 63;
  const int lg = l >> 4, ll = l & 15;
  const int qw0 = q0 + w * 32;

  // Q fragments held in registers (rope already applied)
  bf16x8 qf[2][2];
  {
    const unsigned short* qb = qkv + (size_t)(b * SEQ + qw0) * 3072 + h * 64;
#pragma unroll
    for (int mf = 0; mf < 2; mf++)
#pragma unroll
      for (int kk = 0; kk < 2; kk++)
        qf[mf][kk] = *(const bf16x8*)(qb + (size_t)(mf * 16 + ll) * 3072 + kk * 32 + lg * 8);
  }

  f32x4 oacc[2][4] = {};
  float mrun[2][4], lrun[2][4];
#pragma unroll
  for (int mf = 0; mf < 2; mf++)
#pragma unroll
    for (int r = 0; r < 4; r++) { mrun[mf][r] = -1e30f; lrun[mf][r] = 0.0f; }

  const int qmax_w = qw0 + 31;
  const int kend = q0 + 128;
  for (int k0 = 0; k0 < kend; k0 += 64) {
    // stage K tile: linear LDS dest, swizzled global source (m173 pattern)
#pragma unroll
    for (int i = 0; i < 2; i++) {
      int c = i * 256 + t;
      int kr = c >> 3, cc = c & 7;
      int ccs = cc ^ (kr & 7);
      gl_lds16(qkv + (size_t)(b * SEQ + k0 + kr) * 3072 + 1024 + h * 64 + ccs * 8,
               (char*)Klds + c * 16);
    }
    // stage V transposed [d][key] via registers
    {
      int key = t >> 2, db = (t & 3) * 16;
      const unsigned short* vp = qkv + (size_t)(b * SEQ + k0 + key) * 3072 + 2048 + h * 64 + db;
      union { uint4 u[2]; unsigned short s[16]; } vv;
      vv.u[0] = *(const uint4*)vp;
      vv.u[1] = *(const uint4*)(vp + 8);
#pragma unroll
      for (int i2 = 0; i2 < 16; i2++)
        Vlds[(db + i2) * 72 + key] = vv.s[i2];
    }
    __syncthreads();

    const bool active = (k0 <= qmax_w);
    if (active) {
      // S = Q @ K^T
      f32x4 s[2][4] = {};
#pragma unroll
      for (int kk = 0; kk < 2; kk++) {
#pragma unroll
        for (int nf = 0; nf < 4; nf++) {
          int key = nf * 16 + ll;
          int boff = key * 128 + (kk * 32 + lg * 8) * 2;
          boff ^= (key & 7) << 4;
          bf16x8 kf = *(const bf16x8*)((const char*)Klds + boff);
#pragma unroll
          for (int mf = 0; mf < 2; mf++)
            s[mf][nf] = __builtin_amdgcn_mfma_f32_16x16x32_bf16(qf[mf][kk], kf, s[mf][nf], 0, 0, 0);
        }
      }
      // scale + causal mask
#pragma unroll
      for (int mf = 0; mf < 2; mf++)
#pragma unroll
        for (int nf = 0; nf < 4; nf++) {
          int key = k0 + nf * 16 + ll;
#pragma unroll
          for (int r = 0; r < 4; r++) {
            int qr = qw0 + mf * 16 + lg * 4 + r;
            float v = s[mf][nf][r] * 0.125f;
            s[mf][nf][r] = (key <= qr) ? v : -1e30f;
          }
        }
      // online softmax (16-lane butterfly within row group)
      float alpha[2][4];
#pragma unroll
      for (int mf = 0; mf < 2; mf++)
#pragma unroll
        for (int r = 0; r < 4; r++) {
          float mx = fmaxf(fmaxf(s[mf][0][r], s[mf][1][r]), fmaxf(s[mf][2][r], s[mf][3][r]));
#pragma unroll
          for (int off = 1; off < 16; off <<= 1) mx = fmaxf(mx, __shfl_xor(mx, off));
          float mt = fmaxf(mrun[mf][r], mx);
          alpha[mf][r] = __expf(mrun[mf][r] - mt);
          mrun[mf][r] = mt;
        }
#pragma unroll
      for (int mf = 0; mf < 2; mf++)
#pragma unroll
        for (int r = 0; r < 4; r++) {
          float ps = 0.0f;
#pragma unroll
          for (int nf = 0; nf < 4; nf++) {
            float p = __expf(s[mf][nf][r] - mrun[mf][r]);
            s[mf][nf][r] = p;
            ps += p;
          }
#pragma unroll
          for (int off = 1; off < 16; off <<= 1) ps += __shfl_xor(ps, off);
          lrun[mf][r] = lrun[mf][r] * alpha[mf][r] + ps;
#pragma unroll
          for (int nf = 0; nf < 4; nf++)
            oacc[mf][nf][r] *= alpha[mf][r];
        }
      // write P (bf16) to per-wave LDS
#pragma unroll
      for (int mf = 0; mf < 2; mf++)
#pragma unroll
        for (int nf = 0; nf < 4; nf++)
#pragma unroll
          for (int r = 0; r < 4; r++)
            Plds[w][(mf * 16 + lg * 4 + r) * 72 + nf * 16 + ll] = f2bf(s[mf][nf][r]);
    }
    __syncthreads();
    if (active) {
      // O += P @ V
#pragma unroll
      for (int kk = 0; kk < 2; kk++) {
        bf16x8 pa[2];
#pragma unroll
        for (int mf = 0; mf < 2; mf++)
          pa[mf] = *(const bf16x8*)&Plds[w][(mf * 16 + ll) * 72 + kk * 32 + lg * 8];
#pragma unroll
        for (int nf = 0; nf < 4; nf++) {
          bf16x8 vb = *(const bf16x8*)&Vlds[(nf * 16 + ll) * 72 + kk * 32 + lg * 8];
#pragma unroll
          for (int mf = 0; mf < 2; mf++)
            oacc[mf][nf] = __builtin_amdgcn_mfma_f32_16x16x32_bf16(pa[mf], vb, oacc[mf][nf], 0, 0, 0);
        }
      }
    }
    __syncthreads();
  }

  // normalize + write [b, q, h*64+d] bf16
#pragma unroll
  for (int mf = 0; mf < 2; mf++) {
    float rl[4];
#pragma unroll
    for (int r = 0; r < 4; r++) rl[r] = 1.0f / lrun[mf][r];
#pragma unroll
    for (int nf = 0; nf < 4; nf++)
#pragma unroll
      for (int r = 0; r < 4; r++) {
        int row = qw0 + mf * 16 + lg * 4 + r;
        int col = h * 64 + nf * 16 + ll;
        attn_o[(size_t)(b * SEQ + row) * D_MODEL + col] = f2bf(oacc[mf][nf][r] * rl[r]);
      }
  }
}

// ------------------------------------------------------------------------------
extern "C" void kernel_launch(void* const* d_in, const int* in_sizes, int n_in,
                              void* d_out, int out_size, void* d_ws, size_t ws_size,
                              hipStream_t stream) {
  const float* hidden_states = (const float*)d_in[0];
  // d_in[1] attention_mask: exactly causal, handled analytically
  const float* temb     = (const float*)d_in[2];
  const float* rope_cos = (const float*)d_in[3];
  const float* rope_sin = (const float*)d_in[4];
  const float* ln1_w    = (const float*)d_in[5];
  const float* ln1_b    = (const float*)d_in[6];
  const float* ln2_w    = (const float*)d_in[7];
  const float* ln2_b    = (const float*)d_in[8];
  const float* c_attn_w = (const float*)d_in[9];
  const float* c_attn_b = (const float*)d_in[10];
  const float* c_proj_w = (const float*)d_in[11];
  const float* c_proj_b = (const float*)d_in[12];
  const float* fc_w     = (const float*)d_in[13];
  const float* fc_b     = (const float*)d_in[14];
  const float* proj_w   = (const float*)d_in[15];
  const float* proj_b   = (const float*)d_in[16];
  const float* sst      = (const float*)d_in[17];

  char* ws = (char*)d_ws;
  unsigned short* wqkv  = (unsigned short*)(ws + 0);          //  6.29 MB [3072][1024]
  unsigned short* wproj = (unsigned short*)(ws + 6291456);    //  2.10 MB [1024][1024]
  unsigned short* wfc   = (unsigned short*)(ws + 8388608);    //  8.39 MB [4096][1024]
  unsigned short* wp2   = (unsigned short*)(ws + 16777216);   //  8.39 MB [1024][4096]
  unsigned short* hln   = (unsigned short*)(ws + 25165824);   //  8.39 MB [4096][1024]
  unsigned short* qkvb  = (unsigned short*)(ws + 33554432);   // 25.17 MB [4096][3072]
  unsigned short* attno = (unsigned short*)(ws + 58720256);   //  8.39 MB [4096][1024]
  unsigned short* h3    = (unsigned short*)(ws + 33554432);   // aliases qkvb+attno (dead by then)
  float*          hidden = (float*)(ws + 67108864);           // 16.78 MB f32 [4096][1024]

  dim3 tb(32, 8);
  transpose_convert<<<dim3(3072 / 32, 1024 / 32), tb, 0, stream>>>(c_attn_w, wqkv, 1024, 3072);
  transpose_convert<<<dim3(1024 / 32, 1024 / 32), tb, 0, stream>>>(c_proj_w, wproj, 1024, 1024);
  transpose_convert<<<dim3(4096 / 32, 1024 / 32), tb, 0, stream>>>(fc_w, wfc, 1024, 4096);
  transpose_convert<<<dim3(1024 / 32, 4096 / 32), tb, 0, stream>>>(proj_w, wp2, 4096, 1024);

  ln_mod_kernel<0, 1><<<ROWS, 256, 0, stream>>>(hidden_states, ln1_w, ln1_b, sst, temb, hln);

  gemm_kernel<EPI_BF16><<<dim3(3072 / 128, ROWS / 128), 256, 0, stream>>>(
      hln, wqkv, c_attn_b, qkvb, ROWS, 3072, 1024, nullptr, nullptr, 0, nullptr);

  rope_kernel<<<(ROWS * 1024) / 256, 256, 0, stream>>>(qkvb, rope_cos, rope_sin);

  attn_kernel<<<dim3(SEQ / 128, BATCH * N_HEADS), 256, 0, stream>>>(qkvb, attno);

  gemm_kernel<EPI_RES><<<dim3(1024 / 128, ROWS / 128), 256, 0, stream>>>(
      attno, wproj, c_proj_b, hidden, ROWS, 1024, 1024, sst, temb, 2, hidden_states);

  ln_mod_kernel<3, 4><<<ROWS, 256, 0, stream>>>(hidden, ln2_w, ln2_b, sst, temb, hln);

  gemm_kernel<EPI_GELU><<<dim3(4096 / 128, ROWS / 128), 256, 0, stream>>>(
      hln, wfc, fc_b, h3, ROWS, 4096, 1024, nullptr, nullptr, 0, nullptr);

  gemm_kernel<EPI_FINAL><<<dim3(1024 / 128, ROWS / 128), 256, 0, stream>>>(
      h3, wp2, proj_b, d_out, ROWS, 1024, 4096, sst, temb, 5, hidden);
}

// Round 2
// 343.907 us; speedup vs baseline: 1.0351x; 1.0351x over previous
//
#include <hip/hip_runtime.h>
#include <hip/hip_bf16.h>

#define D_MODEL 1024
#define N_HEADS 16
#define HEAD_DIM 64
#define SEQ 2048
#define BATCH 2
#define INNER_DIM 4096
#define ROWS (BATCH*SEQ)   // 4096

using f32x4  = __attribute__((ext_vector_type(4))) float;
using bf16x8 = __attribute__((ext_vector_type(8))) short;   // 8 bf16 raw bits

__device__ __forceinline__ void gl_lds16(const void* g, void* l) {
  __builtin_amdgcn_global_load_lds(
      (const __attribute__((address_space(1))) void*)g,
      (__attribute__((address_space(3))) void*)l, 16, 0, 0);
}

__device__ __forceinline__ float bf2f(unsigned short u) {
  union { unsigned int i; float f; } v; v.i = ((unsigned int)u) << 16; return v.f;
}
__device__ __forceinline__ unsigned short f2bf(float f) {
  union { float f; unsigned int i; } v; v.f = f;
  unsigned int x = v.i;
  return (unsigned short)((x + 0x7fffu + ((x >> 16) & 1u)) >> 16);  // RTNE
}

__device__ __forceinline__ float gelu_tanh(float x) {
  float x3 = x * x * x;
  float z = 0.7978845608028654f * (x + 0.044715f * x3);
  z = fminf(z, 15.0f);                       // tanh(15)==1, avoid exp overflow
  float e = __expf(2.0f * z);
  float th = (e - 1.0f) / (e + 1.0f);
  return 0.5f * x * (1.0f + th);
}

// ---------------- weight convert + transpose: in[K][N] f32 -> out[N][K] bf16 ----
__global__ void transpose_convert(const float* __restrict__ in,
                                  unsigned short* __restrict__ out,
                                  int K, int N) {
  __shared__ float tile[32][33];
  int n0 = blockIdx.x * 32, k0 = blockIdx.y * 32;
  int tx = threadIdx.x, ty = threadIdx.y;   // 32 x 8
#pragma unroll
  for (int i = 0; i < 4; i++)
    tile[ty + i * 8][tx] = in[(size_t)(k0 + ty + i * 8) * N + n0 + tx];
  __syncthreads();
#pragma unroll
  for (int i = 0; i < 4; i++)
    out[(size_t)(n0 + ty + i * 8) * K + k0 + tx] = f2bf(tile[tx][ty + i * 8]);
}

// ---------------- LayerNorm + adaLN modulation -> bf16 ------------------------
template<int SH_IDX, int SC_IDX>
__global__ void ln_mod_kernel(const float* __restrict__ x,
                              const float* __restrict__ lw,
                              const float* __restrict__ lb,
                              const float* __restrict__ sst,
                              const float* __restrict__ temb,
                              unsigned short* __restrict__ out) {
  int row = blockIdx.x;            // 0..4095
  int b = row >> 11;               // row / 2048
  int t = threadIdx.x;             // 256
  const float* xr = x + (size_t)row * D_MODEL;
  float4 v = ((const float4*)xr)[t];
  float s = v.x + v.y + v.z + v.w;
  float s2 = v.x * v.x + v.y * v.y + v.z * v.z + v.w * v.w;
#pragma unroll
  for (int o = 1; o < 64; o <<= 1) { s += __shfl_xor(s, o); s2 += __shfl_xor(s2, o); }
  __shared__ float red[8];
  int wid = t >> 6, lane = t & 63;
  if (lane == 0) { red[wid] = s; red[4 + wid] = s2; }
  __syncthreads();
  s = red[0] + red[1] + red[2] + red[3];
  s2 = red[4] + red[5] + red[6] + red[7];
  float mu = s * (1.0f / D_MODEL);
  float var = s2 * (1.0f / D_MODEL) - mu * mu;
  float rs = rsqrtf(var + 1e-5f);
  int d0 = t * 4;
  float xv[4] = { v.x, v.y, v.z, v.w };
  ushort4 ov;
  unsigned short* po = (unsigned short*)&ov;
#pragma unroll
  for (int j = 0; j < 4; j++) {
    int d = d0 + j;
    float ln = (xv[j] - mu) * rs * lw[d] + lb[d];
    float sc = sst[SC_IDX * D_MODEL + d] + temb[b * 6 * D_MODEL + SC_IDX * D_MODEL + d];
    float sh = sst[SH_IDX * D_MODEL + d] + temb[b * 6 * D_MODEL + SH_IDX * D_MODEL + d];
    po[j] = f2bf(ln * (1.0f + sc) + sh);
  }
  *((ushort4*)(out + (size_t)row * D_MODEL + d0)) = ov;
}

// ---------------- RoPE in place on q,k halves of qkv --------------------------
__global__ void rope_kernel(unsigned short* __restrict__ qkv,
                            const float* __restrict__ cosb,
                            const float* __restrict__ sinb) {
  int t = blockIdx.x * blockDim.x + threadIdx.x;   // ROWS*1024 pairs (q and k)
  int row = t >> 10;
  int rem = t & 1023;
  int qk = rem >> 9;
  int rem2 = rem & 511;
  int hh = rem2 >> 5;
  int i = rem2 & 31;
  int s = row & (SEQ - 1);
  unsigned int* p = (unsigned int*)(qkv + (size_t)row * 3072 + qk * 1024 + hh * 64 + 2 * i);
  unsigned int pv = *p;
  float xe = bf2f((unsigned short)(pv & 0xffff));
  float xo = bf2f((unsigned short)(pv >> 16));
  float c = cosb[s * 32 + i], sn = sinb[s * 32 + i];
  float oe = xe * c - xo * sn;
  float oo = xe * sn + xo * c;
  *p = (((unsigned int)f2bf(oo)) << 16) | (unsigned int)f2bf(oe);
}

// ---------------- GEMM: C[M,N] = A[M,K] @ Bt[N,K]^T + bias, fused epilogues ---
enum { EPI_BF16 = 0, EPI_RES = 1, EPI_GELU = 2, EPI_FINAL = 3 };

template<int EPI>
__global__ __launch_bounds__(256, 2)
void gemm_kernel(const unsigned short* __restrict__ A,
                 const unsigned short* __restrict__ Bt,
                 const float* __restrict__ bias,
                 void* __restrict__ Cout,
                 int M, int N, int K,
                 const float* __restrict__ sst,
                 const float* __restrict__ temb,
                 int g_idx,
                 const float* __restrict__ res) {
  __shared__ unsigned short Alds[128 * 32];
  __shared__ unsigned short Blds[128 * 32];
  const int t = threadIdx.x;
  const int w = t >> 6, l = t & 63;
  const int lg = l >> 4, ll = l & 15;
  const int wm = w >> 1, wn = w & 1;
  const int m0 = blockIdx.y * 128, n0 = blockIdx.x * 128;

  f32x4 acc[4][4] = {};

  for (int k0 = 0; k0 < K; k0 += 32) {
#pragma unroll
    for (int i = 0; i < 2; i++) {
      int c = i * 256 + t;
      int row = c >> 2, ch = c & 3;
      gl_lds16(A  + (size_t)(m0 + row) * K + k0 + ch * 8, (char*)Alds + c * 16);
      gl_lds16(Bt + (size_t)(n0 + row) * K + k0 + ch * 8, (char*)Blds + c * 16);
    }
    __syncthreads();
    bf16x8 af[4], bfr[4];
#pragma unroll
    for (int mf = 0; mf < 4; mf++)
      af[mf] = *(const bf16x8*)((const char*)Alds + (wm * 64 + mf * 16 + ll) * 64 + lg * 16);
#pragma unroll
    for (int nf = 0; nf < 4; nf++)
      bfr[nf] = *(const bf16x8*)((const char*)Blds + (wn * 64 + nf * 16 + ll) * 64 + lg * 16);
#pragma unroll
    for (int mf = 0; mf < 4; mf++)
#pragma unroll
      for (int nf = 0; nf < 4; nf++)
        acc[mf][nf] = __builtin_amdgcn_mfma_f32_16x16x32_bf16(af[mf], bfr[nf], acc[mf][nf], 0, 0, 0);
    __syncthreads();
  }

#pragma unroll
  for (int mf = 0; mf < 4; mf++) {
#pragma unroll
    for (int nf = 0; nf < 4; nf++) {
      int col = n0 + wn * 64 + nf * 16 + ll;
      float bv = bias[col];
#pragma unroll
      for (int r = 0; r < 4; r++) {
        int row = m0 + wm * 64 + mf * 16 + lg * 4 + r;
        float v = acc[mf][nf][r] + bv;
        if constexpr (EPI == EPI_BF16) {
          ((unsigned short*)Cout)[(size_t)row * N + col] = f2bf(v);
        } else if constexpr (EPI == EPI_GELU) {
          ((unsigned short*)Cout)[(size_t)row * N + col] = f2bf(gelu_tanh(v));
        } else {
          int bb = row >> 11;
          float g = sst[g_idx * D_MODEL + col] + temb[bb * 6 * D_MODEL + g_idx * D_MODEL + col];
          ((float*)Cout)[(size_t)row * N + col] = v * g + res[(size_t)row * N + col];
        }
      }
    }
  }
}

// ---------------- Flash attention (causal), QBLK=64, 64-key tiles -------------
// 1024 blocks (32 q-chunks x 32 bh), 4 waves x 16 q-rows. Only the last k-tile
// (k0==q0) crosses the diagonal -> masking only there. 2 barriers per tile.
__global__ __launch_bounds__(256, 5)
void attn_kernel(const unsigned short* __restrict__ qkv,
                 unsigned short* __restrict__ attn_o) {
  __shared__ unsigned short Klds[64 * 64];      // [key][d], 16B-chunk XOR swizzle
  __shared__ unsigned short Vt[64 * 64];        // [d][key], 16B-chunk XOR swizzle
  __shared__ unsigned short Plds[4][16 * 64];   // per wave [q][key], XOR swizzle

  const int id = blockIdx.x;
  const int bh = id & 31;                 // fast-varying bh: co-resident blocks
  const int b = bh >> 4, h = bh & 15;     // span different causal depths
  const int q0 = (id >> 5) * 64;
  const int t = threadIdx.x;
  const int w = t >> 6, l = t & 63;
  const int lg = l >> 4, ll = l & 15;
  const int qw0 = q0 + w * 16;

  // Q fragments in registers (RoPE already applied). A-frag: lane ll = q-row.
  bf16x8 qf[2];
  {
    const unsigned short* qb = qkv + (size_t)(b * SEQ + qw0 + ll) * 3072 + h * 64;
    qf[0] = *(const bf16x8*)(qb + lg * 8);
    qf[1] = *(const bf16x8*)(qb + 32 + lg * 8);
  }

  f32x4 oacc[4] = {};
  float mrun[4], lrun[4];
#pragma unroll
  for (int r = 0; r < 4; r++) { mrun[r] = -1e30f; lrun[r] = 0.0f; }

  for (int k0 = 0; k0 <= q0; k0 += 64) {
    // ---- stage K tile: linear LDS dest, XOR-swizzled global source ----
#pragma unroll
    for (int i = 0; i < 2; i++) {
      int c = i * 256 + t;
      int kr = c >> 3, cc = c & 7;
      int ccs = cc ^ (kr & 7);
      gl_lds16(qkv + (size_t)(b * SEQ + k0 + kr) * 3072 + 1024 + h * 64 + ccs * 8,
               (char*)Klds + c * 16);
    }
    // ---- stage V^T [d][key]: paired-key packed b32 writes, XOR-chunk swizzle ----
    {
      int kp = t & 31, dg = t >> 5;            // key pair, d-group (8 d's)
      const unsigned short* v0p =
          qkv + (size_t)(b * SEQ + k0 + 2 * kp) * 3072 + 2048 + h * 64 + dg * 8;
      union { uint4 u; unsigned short s[8]; } a0, a1;
      a0.u = *(const uint4*)v0p;
      a1.u = *(const uint4*)(v0p + 3072);
      unsigned int* vt32 = (unsigned int*)Vt;
#pragma unroll
      for (int i = 0; i < 8; i++)               // d = dg*8 + i, d&7 == i
        vt32[(dg * 8 + i) * 32 + (((kp >> 2) ^ i) << 2) + (kp & 3)] =
            (unsigned int)a0.s[i] | ((unsigned int)a1.s[i] << 16);
    }
    __syncthreads();

    // ---- S = Q @ K^T ----
    f32x4 s[4] = {};
#pragma unroll
    for (int kk = 0; kk < 2; kk++) {
#pragma unroll
      for (int nf = 0; nf < 4; nf++) {
        int key = nf * 16 + ll;
        int cc = (kk * 4 + lg) ^ (key & 7);
        bf16x8 kf = *(const bf16x8*)((const char*)Klds + key * 128 + cc * 16);
        s[nf] = __builtin_amdgcn_mfma_f32_16x16x32_bf16(qf[kk], kf, s[nf], 0, 0, 0);
      }
    }
    // ---- scale (+ mask on diagonal tile only) ----
#pragma unroll
    for (int nf = 0; nf < 4; nf++)
#pragma unroll
      for (int r = 0; r < 4; r++) s[nf][r] *= 0.125f;
    if (k0 == q0) {
#pragma unroll
      for (int nf = 0; nf < 4; nf++) {
        int key = k0 + nf * 16 + ll;
#pragma unroll
        for (int r = 0; r < 4; r++)
          if (key > qw0 + lg * 4 + r) s[nf][r] = -1e30f;
      }
    }
    // ---- online softmax (rows = lg*4+r, reduce over 16 ll-lanes) ----
    float alpha[4];
#pragma unroll
    for (int r = 0; r < 4; r++) {
      float mx = fmaxf(fmaxf(s[0][r], s[1][r]), fmaxf(s[2][r], s[3][r]));
#pragma unroll
      for (int o = 1; o < 16; o <<= 1) mx = fmaxf(mx, __shfl_xor(mx, o));
      float mt = fmaxf(mrun[r], mx);
      alpha[r] = __expf(mrun[r] - mt);
      mrun[r] = mt;
    }
#pragma unroll
    for (int r = 0; r < 4; r++) {
      float ps = 0.0f;
#pragma unroll
      for (int nf = 0; nf < 4; nf++) {
        float p = __expf(s[nf][r] - mrun[r]);
        s[nf][r] = p;
        ps += p;
      }
#pragma unroll
      for (int o = 1; o < 16; o <<= 1) ps += __shfl_xor(ps, o);
      lrun[r] = lrun[r] * alpha[r] + ps;
#pragma unroll
      for (int nf = 0; nf < 4; nf++) oacc[nf][r] *= alpha[r];
    }
    // ---- write P (per-wave LDS, no cross-wave barrier needed) ----
#pragma unroll
    for (int nf = 0; nf < 4; nf++) {
      int key = nf * 16 + ll;
#pragma unroll
      for (int r = 0; r < 4; r++) {
        int rho = lg * 4 + r;
        Plds[w][rho * 64 + (((key >> 3) ^ (rho & 7)) << 3) + (key & 7)] = f2bf(s[nf][r]);
      }
    }
    // ---- O += P @ V ----
#pragma unroll
    for (int kk = 0; kk < 2; kk++) {
      bf16x8 pa = *(const bf16x8*)&Plds[w][ll * 64 + (((kk * 4 + lg) ^ (ll & 7)) << 3)];
#pragma unroll
      for (int nf = 0; nf < 4; nf++) {
        int d = nf * 16 + ll;
        bf16x8 vb = *(const bf16x8*)&Vt[d * 64 + (((kk * 4 + lg) ^ (d & 7)) << 3)];
        oacc[nf] = __builtin_amdgcn_mfma_f32_16x16x32_bf16(pa, vb, oacc[nf], 0, 0, 0);
      }
    }
    __syncthreads();
  }

  // ---- normalize + write [b, q, h*64+d] bf16 ----
  float rl[4];
#pragma unroll
  for (int r = 0; r < 4; r++) rl[r] = 1.0f / lrun[r];
#pragma unroll
  for (int nf = 0; nf < 4; nf++)
#pragma unroll
    for (int r = 0; r < 4; r++) {
      int row = qw0 + lg * 4 + r;
      int col = h * 64 + nf * 16 + ll;
      attn_o[(size_t)(b * SEQ + row) * D_MODEL + col] = f2bf(oacc[nf][r] * rl[r]);
    }
}

// ------------------------------------------------------------------------------
extern "C" void kernel_launch(void* const* d_in, const int* in_sizes, int n_in,
                              void* d_out, int out_size, void* d_ws, size_t ws_size,
                              hipStream_t stream) {
  const float* hidden_states = (const float*)d_in[0];
  // d_in[1] attention_mask: exactly causal, handled analytically
  const float* temb     = (const float*)d_in[2];
  const float* rope_cos = (const float*)d_in[3];
  const float* rope_sin = (const float*)d_in[4];
  const float* ln1_w    = (const float*)d_in[5];
  const float* ln1_b    = (const float*)d_in[6];
  const float* ln2_w    = (const float*)d_in[7];
  const float* ln2_b    = (const float*)d_in[8];
  const float* c_attn_w = (const float*)d_in[9];
  const float* c_attn_b = (const float*)d_in[10];
  const float* c_proj_w = (const float*)d_in[11];
  const float* c_proj_b = (const float*)d_in[12];
  const float* fc_w     = (const float*)d_in[13];
  const float* fc_b     = (const float*)d_in[14];
  const float* proj_w   = (const float*)d_in[15];
  const float* proj_b   = (const float*)d_in[16];
  const float* sst      = (const float*)d_in[17];

  char* ws = (char*)d_ws;
  unsigned short* wqkv  = (unsigned short*)(ws + 0);          //  6.29 MB [3072][1024]
  unsigned short* wproj = (unsigned short*)(ws + 6291456);    //  2.10 MB [1024][1024]
  unsigned short* wfc   = (unsigned short*)(ws + 8388608);    //  8.39 MB [4096][1024]
  unsigned short* wp2   = (unsigned short*)(ws + 16777216);   //  8.39 MB [1024][4096]
  unsigned short* hln   = (unsigned short*)(ws + 25165824);   //  8.39 MB [4096][1024]
  unsigned short* qkvb  = (unsigned short*)(ws + 33554432);   // 25.17 MB [4096][3072]
  unsigned short* attno = (unsigned short*)(ws + 58720256);   //  8.39 MB [4096][1024]
  unsigned short* h3    = (unsigned short*)(ws + 33554432);   // aliases qkvb+attno (dead by then)
  float*          hidden = (float*)(ws + 67108864);           // 16.78 MB f32 [4096][1024]

  dim3 tb(32, 8);
  transpose_convert<<<dim3(3072 / 32, 1024 / 32), tb, 0, stream>>>(c_attn_w, wqkv, 1024, 3072);
  transpose_convert<<<dim3(1024 / 32, 1024 / 32), tb, 0, stream>>>(c_proj_w, wproj, 1024, 1024);
  transpose_convert<<<dim3(4096 / 32, 1024 / 32), tb, 0, stream>>>(fc_w, wfc, 1024, 4096);
  transpose_convert<<<dim3(1024 / 32, 4096 / 32), tb, 0, stream>>>(proj_w, wp2, 4096, 1024);

  ln_mod_kernel<0, 1><<<ROWS, 256, 0, stream>>>(hidden_states, ln1_w, ln1_b, sst, temb, hln);

  gemm_kernel<EPI_BF16><<<dim3(3072 / 128, ROWS / 128), 256, 0, stream>>>(
      hln, wqkv, c_attn_b, qkvb, ROWS, 3072, 1024, nullptr, nullptr, 0, nullptr);

  rope_kernel<<<(ROWS * 1024) / 256, 256, 0, stream>>>(qkvb, rope_cos, rope_sin);

  attn_kernel<<<dim3(32 * 32), 256, 0, stream>>>(qkvb, attno);

  gemm_kernel<EPI_RES><<<dim3(1024 / 128, ROWS / 128), 256, 0, stream>>>(
      attno, wproj, c_proj_b, hidden, ROWS, 1024, 1024, sst, temb, 2, hidden_states);

  ln_mod_kernel<3, 4><<<ROWS, 256, 0, stream>>>(hidden, ln2_w, ln2_b, sst, temb, hln);

  gemm_kernel<EPI_GELU><<<dim3(4096 / 128, ROWS / 128), 256, 0, stream>>>(
      hln, wfc, fc_b, h3, ROWS, 4096, 1024, nullptr, nullptr, 0, nullptr);

  gemm_kernel<EPI_FINAL><<<dim3(1024 / 128, ROWS / 128), 256, 0, stream>>>(
      h3, wp2, proj_b, d_out, ROWS, 1024, 4096, sst, temb, 5, hidden);
}

// Round 3
// 286.579 us; speedup vs baseline: 1.2421x; 1.2000x over previous
//
#include <hip/hip_runtime.h>
#include <hip/hip_bf16.h>

#define D_MODEL 1024
#define N_HEADS 16
#define HEAD_DIM 64
#define SEQ 2048
#define BATCH 2
#define INNER_DIM 4096
#define ROWS (BATCH*SEQ)   // 4096

using f32x4  = __attribute__((ext_vector_type(4))) float;
using bf16x8 = __attribute__((ext_vector_type(8))) short;   // 8 bf16 raw bits

__device__ __forceinline__ void gl_lds16(const void* g, void* l) {
  __builtin_amdgcn_global_load_lds(
      (const __attribute__((address_space(1))) void*)g,
      (__attribute__((address_space(3))) void*)l, 16, 0, 0);
}

__device__ __forceinline__ float bf2f(unsigned short u) {
  union { unsigned int i; float f; } v; v.i = ((unsigned int)u) << 16; return v.f;
}
__device__ __forceinline__ unsigned short f2bf(float f) {
  union { float f; unsigned int i; } v; v.f = f;
  unsigned int x = v.i;
  return (unsigned short)((x + 0x7fffu + ((x >> 16) & 1u)) >> 16);  // RTNE
}

__device__ __forceinline__ float exp2fast(float x) {
  return __builtin_amdgcn_exp2f(x);   // v_exp_f32
}

__device__ __forceinline__ float gelu_tanh(float x) {
  float x3 = x * x * x;
  float z = 0.7978845608028654f * (x + 0.044715f * x3);
  z = fminf(z, 15.0f);
  float e = __expf(2.0f * z);
  float th = (e - 1.0f) / (e + 1.0f);
  return 0.5f * x * (1.0f + th);
}

// ---------------- weight convert + transpose: in[K][N] f32 -> out[N][K] bf16 ----
__global__ void transpose_convert(const float* __restrict__ in,
                                  unsigned short* __restrict__ out,
                                  int K, int N) {
  __shared__ float tile[32][33];
  int n0 = blockIdx.x * 32, k0 = blockIdx.y * 32;
  int tx = threadIdx.x, ty = threadIdx.y;   // 32 x 8
#pragma unroll
  for (int i = 0; i < 4; i++)
    tile[ty + i * 8][tx] = in[(size_t)(k0 + ty + i * 8) * N + n0 + tx];
  __syncthreads();
#pragma unroll
  for (int i = 0; i < 4; i++)
    out[(size_t)(n0 + ty + i * 8) * K + k0 + tx] = f2bf(tile[tx][ty + i * 8]);
}

// ---------------- LayerNorm + adaLN modulation -> bf16 ------------------------
template<int SH_IDX, int SC_IDX>
__global__ void ln_mod_kernel(const float* __restrict__ x,
                              const float* __restrict__ lw,
                              const float* __restrict__ lb,
                              const float* __restrict__ sst,
                              const float* __restrict__ temb,
                              unsigned short* __restrict__ out) {
  int row = blockIdx.x;            // 0..4095
  int b = row >> 11;
  int t = threadIdx.x;             // 256
  const float* xr = x + (size_t)row * D_MODEL;
  float4 v = ((const float4*)xr)[t];
  float s = v.x + v.y + v.z + v.w;
  float s2 = v.x * v.x + v.y * v.y + v.z * v.z + v.w * v.w;
#pragma unroll
  for (int o = 1; o < 64; o <<= 1) { s += __shfl_xor(s, o); s2 += __shfl_xor(s2, o); }
  __shared__ float red[8];
  int wid = t >> 6, lane = t & 63;
  if (lane == 0) { red[wid] = s; red[4 + wid] = s2; }
  __syncthreads();
  s = red[0] + red[1] + red[2] + red[3];
  s2 = red[4] + red[5] + red[6] + red[7];
  float mu = s * (1.0f / D_MODEL);
  float var = s2 * (1.0f / D_MODEL) - mu * mu;
  float rs = rsqrtf(var + 1e-5f);
  int d0 = t * 4;
  float xv[4] = { v.x, v.y, v.z, v.w };
  ushort4 ov;
  unsigned short* po = (unsigned short*)&ov;
#pragma unroll
  for (int j = 0; j < 4; j++) {
    int d = d0 + j;
    float ln = (xv[j] - mu) * rs * lw[d] + lb[d];
    float sc = sst[SC_IDX * D_MODEL + d] + temb[b * 6 * D_MODEL + SC_IDX * D_MODEL + d];
    float sh = sst[SH_IDX * D_MODEL + d] + temb[b * 6 * D_MODEL + SH_IDX * D_MODEL + d];
    po[j] = f2bf(ln * (1.0f + sc) + sh);
  }
  *((ushort4*)(out + (size_t)row * D_MODEL + d0)) = ov;
}

// ---------------- RoPE in place; Q half pre-scaled by 0.125*log2(e) -----------
__global__ void rope_kernel(unsigned short* __restrict__ qkv,
                            const float* __restrict__ cosb,
                            const float* __restrict__ sinb) {
  int t = blockIdx.x * blockDim.x + threadIdx.x;
  int row = t >> 10;
  int rem = t & 1023;
  int qk = rem >> 9;
  int rem2 = rem & 511;
  int hh = rem2 >> 5;
  int i = rem2 & 31;
  int s = row & (SEQ - 1);
  unsigned int* p = (unsigned int*)(qkv + (size_t)row * 3072 + qk * 1024 + hh * 64 + 2 * i);
  unsigned int pv = *p;
  float xe = bf2f((unsigned short)(pv & 0xffff));
  float xo = bf2f((unsigned short)(pv >> 16));
  float c = cosb[s * 32 + i], sn = sinb[s * 32 + i];
  float sc = (qk == 0) ? 0.18033688011112042f : 1.0f;  // 0.125*log2e on Q only
  float oe = (xe * c - xo * sn) * sc;
  float oo = (xe * sn + xo * c) * sc;
  *p = (((unsigned int)f2bf(oo)) << 16) | (unsigned int)f2bf(oe);
}

// ---------------- GEMM: C[M,N] = A[M,K] @ Bt[N,K]^T + bias, fused epilogues ---
// BMF = m-fragments per wave; tile = (BMF*32) x 128.
enum { EPI_BF16 = 0, EPI_RES = 1, EPI_GELU = 2, EPI_FINAL = 3 };

template<int EPI, int BMF>
__global__ __launch_bounds__(256, 2)
void gemm_kernel(const unsigned short* __restrict__ A,
                 const unsigned short* __restrict__ Bt,
                 const float* __restrict__ bias,
                 void* __restrict__ Cout,
                 int N, int K,
                 const float* __restrict__ sst,
                 const float* __restrict__ temb,
                 int g_idx,
                 const float* __restrict__ res) {
  __shared__ unsigned short Alds[BMF * 32 * 32];
  __shared__ unsigned short Blds[128 * 32];
  const int t = threadIdx.x;
  const int w = t >> 6, l = t & 63;
  const int lg = l >> 4, ll = l & 15;
  const int wm = w >> 1, wn = w & 1;
  const int m0 = blockIdx.y * (BMF * 32), n0 = blockIdx.x * 128;

  f32x4 acc[BMF][4] = {};

  for (int k0 = 0; k0 < K; k0 += 32) {
#pragma unroll
    for (int i = 0; i < BMF / 2; i++) {
      int c = i * 256 + t;
      int row = c >> 2, ch = c & 3;
      gl_lds16(A + (size_t)(m0 + row) * K + k0 + ch * 8, (char*)Alds + c * 16);
    }
#pragma unroll
    for (int i = 0; i < 2; i++) {
      int c = i * 256 + t;
      int row = c >> 2, ch = c & 3;
      gl_lds16(Bt + (size_t)(n0 + row) * K + k0 + ch * 8, (char*)Blds + c * 16);
    }
    __syncthreads();
    bf16x8 af[BMF], bfr[4];
#pragma unroll
    for (int mf = 0; mf < BMF; mf++)
      af[mf] = *(const bf16x8*)((const char*)Alds + (wm * (BMF * 16) + mf * 16 + ll) * 64 + lg * 16);
#pragma unroll
    for (int nf = 0; nf < 4; nf++)
      bfr[nf] = *(const bf16x8*)((const char*)Blds + (wn * 64 + nf * 16 + ll) * 64 + lg * 16);
#pragma unroll
    for (int mf = 0; mf < BMF; mf++)
#pragma unroll
      for (int nf = 0; nf < 4; nf++)
        acc[mf][nf] = __builtin_amdgcn_mfma_f32_16x16x32_bf16(af[mf], bfr[nf], acc[mf][nf], 0, 0, 0);
    __syncthreads();
  }

#pragma unroll
  for (int mf = 0; mf < BMF; mf++) {
#pragma unroll
    for (int nf = 0; nf < 4; nf++) {
      int col = n0 + wn * 64 + nf * 16 + ll;
      float bv = bias[col];
#pragma unroll
      for (int r = 0; r < 4; r++) {
        int row = m0 + wm * (BMF * 16) + mf * 16 + lg * 4 + r;
        float v = acc[mf][nf][r] + bv;
        if constexpr (EPI == EPI_BF16) {
          ((unsigned short*)Cout)[(size_t)row * N + col] = f2bf(v);
        } else if constexpr (EPI == EPI_GELU) {
          ((unsigned short*)Cout)[(size_t)row * N + col] = f2bf(gelu_tanh(v));
        } else {
          int bb = row >> 11;
          float g = sst[g_idx * D_MODEL + col] + temb[bb * 6 * D_MODEL + g_idx * D_MODEL + col];
          ((float*)Cout)[(size_t)row * N + col] = v * g + res[(size_t)row * N + col];
        }
      }
    }
  }
}

// ---------------- Flash attention (causal), swapped-operand softmax -----------
// S^T = mfma(K,Q): lane owns q=ll, 16 in-lane S values -> scalar m/l per lane,
// 2 shuffles per reduction. PV swapped too: O^T = mfma(V^T, P^T) keeps q=ll.
// Double-buffered K/V, 1 barrier/tile, next-tile loads issued before compute.
__global__ __launch_bounds__(256, 4)
void attn_kernel(const unsigned short* __restrict__ qkv,
                 unsigned short* __restrict__ attn_o) {
  __shared__ unsigned short Klds[2][64 * 64];   // [key][d], 16B-chunk XOR swizzle
  __shared__ unsigned short Vt[2][64 * 64];     // [d][key], 16B-chunk XOR swizzle
  __shared__ unsigned short Plds[4][16 * 64];   // per wave [q][key], XOR swizzle

  const int id = blockIdx.x;
  const int bh = id & 31;
  const int b = bh >> 4, h = bh & 15;
  const int q0 = (id >> 5) * 64;
  const int t = threadIdx.x;
  const int w = t >> 6, l = t & 63;
  const int lg = l >> 4, ll = l & 15;
  const int qw0 = q0 + w * 16;
  const int q_lane = qw0 + ll;

  // Q regs; as B-frag: col=q=ll, k-slice d=lg*8..+7 (Q pre-scaled by rope)
  bf16x8 qf[2];
  {
    const unsigned short* qb = qkv + (size_t)(b * SEQ + q_lane) * 3072 + h * 64;
    qf[0] = *(const bf16x8*)(qb + lg * 8);
    qf[1] = *(const bf16x8*)(qb + 32 + lg * 8);
  }

  const int kp = t & 31, dg = t >> 5;   // V-stage: keys 2kp,2kp+1; d-group dg*8..

  f32x4 oacc[4] = {};
  float mrun = -1e30f, lrun = 0.0f;

  // ---- prologue: stage tile 0 into buf 0 ----
  {
#pragma unroll
    for (int i = 0; i < 2; i++) {
      int c = i * 256 + t;
      int kr = c >> 3, cc = c & 7;
      gl_lds16(qkv + (size_t)(b * SEQ + kr) * 3072 + 1024 + h * 64 + (cc ^ (kr & 7)) * 8,
               (char*)&Klds[0][0] + c * 16);
    }
    const unsigned short* vp = qkv + (size_t)(b * SEQ + 2 * kp) * 3072 + 2048 + h * 64 + dg * 8;
    union { uint4 u; unsigned short s[8]; } a0, a1;
    a0.u = *(const uint4*)vp;
    a1.u = *(const uint4*)(vp + 3072);
    unsigned int* vt32 = (unsigned int*)&Vt[0][0];
#pragma unroll
    for (int i = 0; i < 8; i++)
      vt32[(dg * 8 + i) * 32 + (((kp >> 2) ^ i) << 2) + (kp & 3)] =
          (unsigned int)a0.s[i] | ((unsigned int)a1.s[i] << 16);
  }
  __syncthreads();

  int buf = 0;
  for (int k0 = 0; k0 <= q0; k0 += 64) {
    const bool has_next = (k0 + 64 <= q0);
    // ---- issue next-tile loads early (overlap with compute) ----
    union { uint4 u; unsigned short s[8]; } n0, n1;
    if (has_next) {
#pragma unroll
      for (int i = 0; i < 2; i++) {
        int c = i * 256 + t;
        int kr = c >> 3, cc = c & 7;
        gl_lds16(qkv + (size_t)(b * SEQ + k0 + 64 + kr) * 3072 + 1024 + h * 64 + (cc ^ (kr & 7)) * 8,
                 (char*)&Klds[buf ^ 1][0] + c * 16);
      }
      const unsigned short* vp =
          qkv + (size_t)(b * SEQ + k0 + 64 + 2 * kp) * 3072 + 2048 + h * 64 + dg * 8;
      n0.u = *(const uint4*)vp;
      n1.u = *(const uint4*)(vp + 3072);
    }

    // ---- S^T = mfma(K, Q): lane -> q=ll, key=k0+nf*16+lg*4+r ----
    f32x4 s[4] = {};
#pragma unroll
    for (int kk = 0; kk < 2; kk++) {
#pragma unroll
      for (int nf = 0; nf < 4; nf++) {
        int key = nf * 16 + ll;
        int cc = (kk * 4 + lg) ^ (key & 7);
        bf16x8 kf = *(const bf16x8*)((const char*)&Klds[buf][0] + key * 128 + cc * 16);
        s[nf] = __builtin_amdgcn_mfma_f32_16x16x32_bf16(kf, qf[kk], s[nf], 0, 0, 0);
      }
    }
    // ---- causal mask (diagonal tile only) ----
    if (k0 == q0) {
#pragma unroll
      for (int nf = 0; nf < 4; nf++) {
        int key = k0 + nf * 16 + lg * 4;
#pragma unroll
        for (int r = 0; r < 4; r++)
          if (key + r > q_lane) s[nf][r] = -1e30f;
      }
    }
    // ---- online softmax: in-lane over 16 values + 2 shuffles (lg groups) ----
    float mx = -1e30f;
#pragma unroll
    for (int nf = 0; nf < 4; nf++)
#pragma unroll
      for (int r = 0; r < 4; r++) mx = fmaxf(mx, s[nf][r]);
    mx = fmaxf(mx, __shfl_xor(mx, 16));
    mx = fmaxf(mx, __shfl_xor(mx, 32));
    float mnew = fmaxf(mrun, mx);
    float alpha = exp2fast(mrun - mnew);
    mrun = mnew;
    float ps = 0.0f;
#pragma unroll
    for (int nf = 0; nf < 4; nf++)
#pragma unroll
      for (int r = 0; r < 4; r++) {
        float p = exp2fast(s[nf][r] - mnew);
        s[nf][r] = p;
        ps += p;
      }
    ps += __shfl_xor(ps, 16);
    ps += __shfl_xor(ps, 32);
    lrun = lrun * alpha + ps;
#pragma unroll
    for (int nf = 0; nf < 4; nf++)
#pragma unroll
      for (int r = 0; r < 4; r++) oacc[nf][r] *= alpha;

    // ---- P^T write: 4 consecutive keys -> one b64 per nf ----
#pragma unroll
    for (int nf = 0; nf < 4; nf++) {
      unsigned int lo = (unsigned int)f2bf(s[nf][0]) | ((unsigned int)f2bf(s[nf][1]) << 16);
      unsigned int hi = (unsigned int)f2bf(s[nf][2]) | ((unsigned int)f2bf(s[nf][3]) << 16);
      int chunk = (nf * 2 + (lg >> 1)) ^ (ll & 7);
      uint2 pv; pv.x = lo; pv.y = hi;
      *(uint2*)((char*)&Plds[w][0] + ll * 128 + chunk * 16 + (lg & 1) * 8) = pv;
    }
    // ---- O^T += mfma(V^T, P^T): lane -> q=ll, d=nf*16+lg*4+r ----
    bf16x8 pb[2];
#pragma unroll
    for (int kk = 0; kk < 2; kk++) {
      int pc = (kk * 4 + lg) ^ (ll & 7);
      pb[kk] = *(const bf16x8*)((char*)&Plds[w][0] + ll * 128 + pc * 16);
    }
#pragma unroll
    for (int nf = 0; nf < 4; nf++) {
      int d = nf * 16 + ll;
#pragma unroll
      for (int kk = 0; kk < 2; kk++) {
        int vc = (kk * 4 + lg) ^ (d & 7);
        bf16x8 vb = *(const bf16x8*)((const char*)&Vt[buf][0] + d * 128 + vc * 16);
        oacc[nf] = __builtin_amdgcn_mfma_f32_16x16x32_bf16(vb, pb[kk], oacc[nf], 0, 0, 0);
      }
    }
    // ---- write next V tile, single barrier ----
    if (has_next) {
      unsigned int* vt32 = (unsigned int*)&Vt[buf ^ 1][0];
#pragma unroll
      for (int i = 0; i < 8; i++)
        vt32[(dg * 8 + i) * 32 + (((kp >> 2) ^ i) << 2) + (kp & 3)] =
            (unsigned int)n0.s[i] | ((unsigned int)n1.s[i] << 16);
    }
    __syncthreads();
    buf ^= 1;
  }

  // ---- normalize + write: lane q=ll, d=nf*16+lg*4+r -> 8B packed stores ----
  float rl = 1.0f / lrun;
#pragma unroll
  for (int nf = 0; nf < 4; nf++) {
    ushort4 ov;
    ov.x = f2bf(oacc[nf][0] * rl);
    ov.y = f2bf(oacc[nf][1] * rl);
    ov.z = f2bf(oacc[nf][2] * rl);
    ov.w = f2bf(oacc[nf][3] * rl);
    *(ushort4*)(attn_o + (size_t)(b * SEQ + q_lane) * D_MODEL + h * 64 + nf * 16 + lg * 4) = ov;
  }
}

// ------------------------------------------------------------------------------
extern "C" void kernel_launch(void* const* d_in, const int* in_sizes, int n_in,
                              void* d_out, int out_size, void* d_ws, size_t ws_size,
                              hipStream_t stream) {
  const float* hidden_states = (const float*)d_in[0];
  const float* temb     = (const float*)d_in[2];
  const float* rope_cos = (const float*)d_in[3];
  const float* rope_sin = (const float*)d_in[4];
  const float* ln1_w    = (const float*)d_in[5];
  const float* ln1_b    = (const float*)d_in[6];
  const float* ln2_w    = (const float*)d_in[7];
  const float* ln2_b    = (const float*)d_in[8];
  const float* c_attn_w = (const float*)d_in[9];
  const float* c_attn_b = (const float*)d_in[10];
  const float* c_proj_w = (const float*)d_in[11];
  const float* c_proj_b = (const float*)d_in[12];
  const float* fc_w     = (const float*)d_in[13];
  const float* fc_b     = (const float*)d_in[14];
  const float* proj_w   = (const float*)d_in[15];
  const float* proj_b   = (const float*)d_in[16];
  const float* sst      = (const float*)d_in[17];

  char* ws = (char*)d_ws;
  unsigned short* wqkv  = (unsigned short*)(ws + 0);
  unsigned short* wproj = (unsigned short*)(ws + 6291456);
  unsigned short* wfc   = (unsigned short*)(ws + 8388608);
  unsigned short* wp2   = (unsigned short*)(ws + 16777216);
  unsigned short* hln   = (unsigned short*)(ws + 25165824);
  unsigned short* qkvb  = (unsigned short*)(ws + 33554432);
  unsigned short* attno = (unsigned short*)(ws + 58720256);
  unsigned short* h3    = (unsigned short*)(ws + 33554432);   // aliases qkvb+attno
  float*          hidden = (float*)(ws + 67108864);

  dim3 tb(32, 8);
  transpose_convert<<<dim3(3072 / 32, 1024 / 32), tb, 0, stream>>>(c_attn_w, wqkv, 1024, 3072);
  transpose_convert<<<dim3(1024 / 32, 1024 / 32), tb, 0, stream>>>(c_proj_w, wproj, 1024, 1024);
  transpose_convert<<<dim3(4096 / 32, 1024 / 32), tb, 0, stream>>>(fc_w, wfc, 1024, 4096);
  transpose_convert<<<dim3(1024 / 32, 4096 / 32), tb, 0, stream>>>(proj_w, wp2, 4096, 1024);

  ln_mod_kernel<0, 1><<<ROWS, 256, 0, stream>>>(hidden_states, ln1_w, ln1_b, sst, temb, hln);

  gemm_kernel<EPI_BF16, 4><<<dim3(3072 / 128, ROWS / 128), 256, 0, stream>>>(
      hln, wqkv, c_attn_b, qkvb, 3072, 1024, nullptr, nullptr, 0, nullptr);

  rope_kernel<<<(ROWS * 1024) / 256, 256, 0, stream>>>(qkvb, rope_cos, rope_sin);

  attn_kernel<<<dim3(32 * 32), 256, 0, stream>>>(qkvb, attno);

  gemm_kernel<EPI_RES, 2><<<dim3(1024 / 128, ROWS / 64), 256, 0, stream>>>(
      attno, wproj, c_proj_b, hidden, 1024, 1024, sst, temb, 2, hidden_states);

  ln_mod_kernel<3, 4><<<ROWS, 256, 0, stream>>>(hidden, ln2_w, ln2_b, sst, temb, hln);

  gemm_kernel<EPI_GELU, 4><<<dim3(4096 / 128, ROWS / 128), 256, 0, stream>>>(
      hln, wfc, fc_b, h3, 4096, 1024, nullptr, nullptr, 0, nullptr);

  gemm_kernel<EPI_FINAL, 2><<<dim3(1024 / 128, ROWS / 64), 256, 0, stream>>>(
      h3, wp2, proj_b, d_out, 1024, 4096, sst, temb, 5, hidden);
}

// Round 4
// 283.849 us; speedup vs baseline: 1.2541x; 1.0096x over previous
//
#include <hip/hip_runtime.h>
#include <hip/hip_bf16.h>

#define D_MODEL 1024
#define N_HEADS 16
#define HEAD_DIM 64
#define SEQ 2048
#define BATCH 2
#define INNER_DIM 4096
#define ROWS (BATCH*SEQ)   // 4096

using f32x4  = __attribute__((ext_vector_type(4))) float;
using bf16x8 = __attribute__((ext_vector_type(8))) short;   // 8 bf16 raw bits

__device__ __forceinline__ void gl_lds16(const void* g, void* l) {
  __builtin_amdgcn_global_load_lds(
      (const __attribute__((address_space(1))) void*)g,
      (__attribute__((address_space(3))) void*)l, 16, 0, 0);
}

__device__ __forceinline__ float bf2f(unsigned short u) {
  union { unsigned int i; float f; } v; v.i = ((unsigned int)u) << 16; return v.f;
}
__device__ __forceinline__ unsigned short f2bf(float f) {
  union { float f; unsigned int i; } v; v.f = f;
  unsigned int x = v.i;
  return (unsigned short)((x + 0x7fffu + ((x >> 16) & 1u)) >> 16);  // RTNE
}

__device__ __forceinline__ float exp2fast(float x) {
  return __builtin_amdgcn_exp2f(x);   // v_exp_f32
}

__device__ __forceinline__ float gelu_tanh(float x) {
  float x3 = x * x * x;
  float z = 0.7978845608028654f * (x + 0.044715f * x3);
  z = fminf(z, 15.0f);
  float e = __expf(2.0f * z);
  float th = (e - 1.0f) / (e + 1.0f);
  return 0.5f * x * (1.0f + th);
}

// ---------------- weight convert + transpose: in[K][N] f32 -> out[N][K] bf16 ----
__global__ void transpose_convert(const float* __restrict__ in,
                                  unsigned short* __restrict__ out,
                                  int K, int N) {
  __shared__ float tile[32][33];
  int n0 = blockIdx.x * 32, k0 = blockIdx.y * 32;
  int tx = threadIdx.x, ty = threadIdx.y;   // 32 x 8
#pragma unroll
  for (int i = 0; i < 4; i++)
    tile[ty + i * 8][tx] = in[(size_t)(k0 + ty + i * 8) * N + n0 + tx];
  __syncthreads();
#pragma unroll
  for (int i = 0; i < 4; i++)
    out[(size_t)(n0 + ty + i * 8) * K + k0 + tx] = f2bf(tile[tx][ty + i * 8]);
}

// ---------------- LayerNorm + adaLN modulation -> bf16 ------------------------
template<int SH_IDX, int SC_IDX>
__global__ void ln_mod_kernel(const float* __restrict__ x,
                              const float* __restrict__ lw,
                              const float* __restrict__ lb,
                              const float* __restrict__ sst,
                              const float* __restrict__ temb,
                              unsigned short* __restrict__ out) {
  int row = blockIdx.x;            // 0..4095
  int b = row >> 11;
  int t = threadIdx.x;             // 256
  const float* xr = x + (size_t)row * D_MODEL;
  float4 v = ((const float4*)xr)[t];
  float s = v.x + v.y + v.z + v.w;
  float s2 = v.x * v.x + v.y * v.y + v.z * v.z + v.w * v.w;
#pragma unroll
  for (int o = 1; o < 64; o <<= 1) { s += __shfl_xor(s, o); s2 += __shfl_xor(s2, o); }
  __shared__ float red[8];
  int wid = t >> 6, lane = t & 63;
  if (lane == 0) { red[wid] = s; red[4 + wid] = s2; }
  __syncthreads();
  s = red[0] + red[1] + red[2] + red[3];
  s2 = red[4] + red[5] + red[6] + red[7];
  float mu = s * (1.0f / D_MODEL);
  float var = s2 * (1.0f / D_MODEL) - mu * mu;
  float rs = rsqrtf(var + 1e-5f);
  int d0 = t * 4;
  float xv[4] = { v.x, v.y, v.z, v.w };
  ushort4 ov;
  unsigned short* po = (unsigned short*)&ov;
#pragma unroll
  for (int j = 0; j < 4; j++) {
    int d = d0 + j;
    float ln = (xv[j] - mu) * rs * lw[d] + lb[d];
    float sc = sst[SC_IDX * D_MODEL + d] + temb[b * 6 * D_MODEL + SC_IDX * D_MODEL + d];
    float sh = sst[SH_IDX * D_MODEL + d] + temb[b * 6 * D_MODEL + SH_IDX * D_MODEL + d];
    po[j] = f2bf(ln * (1.0f + sc) + sh);
  }
  *((ushort4*)(out + (size_t)row * D_MODEL + d0)) = ov;
}

// ---------------- RoPE in place; Q half pre-scaled by 0.125*log2(e) -----------
__global__ void rope_kernel(unsigned short* __restrict__ qkv,
                            const float* __restrict__ cosb,
                            const float* __restrict__ sinb) {
  int t = blockIdx.x * blockDim.x + threadIdx.x;
  int row = t >> 10;
  int rem = t & 1023;
  int qk = rem >> 9;
  int rem2 = rem & 511;
  int hh = rem2 >> 5;
  int i = rem2 & 31;
  int s = row & (SEQ - 1);
  unsigned int* p = (unsigned int*)(qkv + (size_t)row * 3072 + qk * 1024 + hh * 64 + 2 * i);
  unsigned int pv = *p;
  float xe = bf2f((unsigned short)(pv & 0xffff));
  float xo = bf2f((unsigned short)(pv >> 16));
  float c = cosb[s * 32 + i], sn = sinb[s * 32 + i];
  float sc = (qk == 0) ? 0.18033688011112042f : 1.0f;  // 0.125*log2e on Q only
  float oe = (xe * c - xo * sn) * sc;
  float oo = (xe * sn + xo * c) * sc;
  *p = (((unsigned int)f2bf(oo)) << 16) | (unsigned int)f2bf(oe);
}

// ---------------- GEMM: C[M,N] = A[M,K] @ Bt[N,K]^T + bias, fused epilogues ---
// Double-buffered LDS, counted-vmcnt prefetch (T4), chunk-swizzled LDS (T2),
// XCD-aware block remap (T1). Tile = (BMF*32) x 128, 4 waves (2x2).
enum { EPI_BF16 = 0, EPI_RES = 1, EPI_GELU = 2, EPI_FINAL = 3 };

template<int EPI, int BMF>
__global__ __launch_bounds__(256, 2)
void gemm_kernel(const unsigned short* __restrict__ A,
                 const unsigned short* __restrict__ Bt,
                 const float* __restrict__ bias,
                 void* __restrict__ Cout,
                 int N, int K,
                 const float* __restrict__ sst,
                 const float* __restrict__ temb,
                 int g_idx,
                 const float* __restrict__ res) {
  __shared__ unsigned short Alds[2][BMF * 32 * 32];
  __shared__ unsigned short Blds[2][128 * 32];
  const int t = threadIdx.x;
  const int w = t >> 6, l = t & 63;
  const int lg = l >> 4, ll = l & 15;
  const int wm = w >> 1, wn = w & 1;

  // T1: bijective XCD-chunked remap of the flattened block id (nwg % 8 == 0)
  const int nx = gridDim.x;
  const int nwg = nx * gridDim.y;
  const int lid = blockIdx.y * nx + blockIdx.x;
  const int nid = (lid & 7) * (nwg >> 3) + (lid >> 3);
  const int m0 = (nid / nx) * (BMF * 32), n0 = (nid % nx) * 128;

  f32x4 acc[BMF][4] = {};

  // stage tile (k0) into buffer buf; LDS dest linear, global source chunk-swizzled
  auto stage = [&](int k0, int buf) {
#pragma unroll
    for (int i = 0; i < BMF / 2; i++) {
      int c = i * 256 + t;
      int row = c >> 2, ch = c & 3;
      int chs = ch ^ ((row >> 1) & 3);
      gl_lds16(A + (size_t)(m0 + row) * K + k0 + chs * 8, (char*)&Alds[buf][0] + c * 16);
    }
#pragma unroll
    for (int i = 0; i < 2; i++) {
      int c = i * 256 + t;
      int row = c >> 2, ch = c & 3;
      int chs = ch ^ ((row >> 1) & 3);
      gl_lds16(Bt + (size_t)(n0 + row) * K + k0 + chs * 8, (char*)&Blds[buf][0] + c * 16);
    }
  };

  stage(0, 0);
  int buf = 0;
  for (int k0 = 0; k0 < K; k0 += 32) {
    const bool hn = (k0 + 32 < K);
    if (hn) {
      stage(k0 + 32, buf ^ 1);
      // wait only for the CURRENT tile: the (BMF/2+2) newest loads stay in flight
      if constexpr (BMF == 4) asm volatile("s_waitcnt vmcnt(4)" ::: "memory");
      else                    asm volatile("s_waitcnt vmcnt(3)" ::: "memory");
    } else {
      asm volatile("s_waitcnt vmcnt(0)" ::: "memory");
    }
    __builtin_amdgcn_s_barrier();
    asm volatile("" ::: "memory");

    bf16x8 af[BMF], bfr[4];
#pragma unroll
    for (int mf = 0; mf < BMF; mf++) {
      int row = wm * (BMF * 16) + mf * 16 + ll;
      int ch = lg ^ ((row >> 1) & 3);
      af[mf] = *(const bf16x8*)((const char*)&Alds[buf][0] + row * 64 + ch * 16);
    }
#pragma unroll
    for (int nf = 0; nf < 4; nf++) {
      int row = wn * 64 + nf * 16 + ll;
      int ch = lg ^ ((row >> 1) & 3);
      bfr[nf] = *(const bf16x8*)((const char*)&Blds[buf][0] + row * 64 + ch * 16);
    }
#pragma unroll
    for (int mf = 0; mf < BMF; mf++)
#pragma unroll
      for (int nf = 0; nf < 4; nf++)
        acc[mf][nf] = __builtin_amdgcn_mfma_f32_16x16x32_bf16(af[mf], bfr[nf], acc[mf][nf], 0, 0, 0);

    asm volatile("" ::: "memory");
    __builtin_amdgcn_s_barrier();   // reads of buf done before next stage overwrites
    buf ^= 1;
  }

#pragma unroll
  for (int mf = 0; mf < BMF; mf++) {
#pragma unroll
    for (int nf = 0; nf < 4; nf++) {
      int col = n0 + wn * 64 + nf * 16 + ll;
      float bv = bias[col];
#pragma unroll
      for (int r = 0; r < 4; r++) {
        int row = m0 + wm * (BMF * 16) + mf * 16 + lg * 4 + r;
        float v = acc[mf][nf][r] + bv;
        if constexpr (EPI == EPI_BF16) {
          ((unsigned short*)Cout)[(size_t)row * N + col] = f2bf(v);
        } else if constexpr (EPI == EPI_GELU) {
          ((unsigned short*)Cout)[(size_t)row * N + col] = f2bf(gelu_tanh(v));
        } else {
          int bb = row >> 11;
          float g = sst[g_idx * D_MODEL + col] + temb[bb * 6 * D_MODEL + g_idx * D_MODEL + col];
          ((float*)Cout)[(size_t)row * N + col] = v * g + res[(size_t)row * N + col];
        }
      }
    }
  }
}

// ---------------- Flash attention (causal), swapped-operand softmax -----------
__global__ __launch_bounds__(256, 4)
void attn_kernel(const unsigned short* __restrict__ qkv,
                 unsigned short* __restrict__ attn_o) {
  __shared__ unsigned short Klds[2][64 * 64];   // [key][d], 16B-chunk XOR swizzle
  __shared__ unsigned short Vt[2][64 * 64];     // [d][key], 16B-chunk XOR swizzle
  __shared__ unsigned short Plds[4][16 * 64];   // per wave [q][key], XOR swizzle

  const int id = blockIdx.x;
  const int bh = id & 31;
  const int b = bh >> 4, h = bh & 15;
  const int q0 = (id >> 5) * 64;
  const int t = threadIdx.x;
  const int w = t >> 6, l = t & 63;
  const int lg = l >> 4, ll = l & 15;
  const int qw0 = q0 + w * 16;
  const int q_lane = qw0 + ll;

  bf16x8 qf[2];
  {
    const unsigned short* qb = qkv + (size_t)(b * SEQ + q_lane) * 3072 + h * 64;
    qf[0] = *(const bf16x8*)(qb + lg * 8);
    qf[1] = *(const bf16x8*)(qb + 32 + lg * 8);
  }

  const int kp = t & 31, dg = t >> 5;

  f32x4 oacc[4] = {};
  float mrun = -1e30f, lrun = 0.0f;

  {
#pragma unroll
    for (int i = 0; i < 2; i++) {
      int c = i * 256 + t;
      int kr = c >> 3, cc = c & 7;
      gl_lds16(qkv + (size_t)(b * SEQ + kr) * 3072 + 1024 + h * 64 + (cc ^ (kr & 7)) * 8,
               (char*)&Klds[0][0] + c * 16);
    }
    const unsigned short* vp = qkv + (size_t)(b * SEQ + 2 * kp) * 3072 + 2048 + h * 64 + dg * 8;
    union { uint4 u; unsigned short s[8]; } a0, a1;
    a0.u = *(const uint4*)vp;
    a1.u = *(const uint4*)(vp + 3072);
    unsigned int* vt32 = (unsigned int*)&Vt[0][0];
#pragma unroll
    for (int i = 0; i < 8; i++)
      vt32[(dg * 8 + i) * 32 + (((kp >> 2) ^ i) << 2) + (kp & 3)] =
          (unsigned int)a0.s[i] | ((unsigned int)a1.s[i] << 16);
  }
  __syncthreads();

  int buf = 0;
  for (int k0 = 0; k0 <= q0; k0 += 64) {
    const bool has_next = (k0 + 64 <= q0);
    union { uint4 u; unsigned short s[8]; } n0, n1;
    if (has_next) {
#pragma unroll
      for (int i = 0; i < 2; i++) {
        int c = i * 256 + t;
        int kr = c >> 3, cc = c & 7;
        gl_lds16(qkv + (size_t)(b * SEQ + k0 + 64 + kr) * 3072 + 1024 + h * 64 + (cc ^ (kr & 7)) * 8,
                 (char*)&Klds[buf ^ 1][0] + c * 16);
      }
      const unsigned short* vp =
          qkv + (size_t)(b * SEQ + k0 + 64 + 2 * kp) * 3072 + 2048 + h * 64 + dg * 8;
      n0.u = *(const uint4*)vp;
      n1.u = *(const uint4*)(vp + 3072);
    }

    f32x4 s[4] = {};
#pragma unroll
    for (int kk = 0; kk < 2; kk++) {
#pragma unroll
      for (int nf = 0; nf < 4; nf++) {
        int key = nf * 16 + ll;
        int cc = (kk * 4 + lg) ^ (key & 7);
        bf16x8 kf = *(const bf16x8*)((const char*)&Klds[buf][0] + key * 128 + cc * 16);
        s[nf] = __builtin_amdgcn_mfma_f32_16x16x32_bf16(kf, qf[kk], s[nf], 0, 0, 0);
      }
    }
    if (k0 == q0) {
#pragma unroll
      for (int nf = 0; nf < 4; nf++) {
        int key = k0 + nf * 16 + lg * 4;
#pragma unroll
        for (int r = 0; r < 4; r++)
          if (key + r > q_lane) s[nf][r] = -1e30f;
      }
    }
    float mx = -1e30f;
#pragma unroll
    for (int nf = 0; nf < 4; nf++)
#pragma unroll
      for (int r = 0; r < 4; r++) mx = fmaxf(mx, s[nf][r]);
    mx = fmaxf(mx, __shfl_xor(mx, 16));
    mx = fmaxf(mx, __shfl_xor(mx, 32));
    float mnew = fmaxf(mrun, mx);
    float alpha = exp2fast(mrun - mnew);
    mrun = mnew;
    float ps = 0.0f;
#pragma unroll
    for (int nf = 0; nf < 4; nf++)
#pragma unroll
      for (int r = 0; r < 4; r++) {
        float p = exp2fast(s[nf][r] - mnew);
        s[nf][r] = p;
        ps += p;
      }
    ps += __shfl_xor(ps, 16);
    ps += __shfl_xor(ps, 32);
    lrun = lrun * alpha + ps;
#pragma unroll
    for (int nf = 0; nf < 4; nf++)
#pragma unroll
      for (int r = 0; r < 4; r++) oacc[nf][r] *= alpha;

#pragma unroll
    for (int nf = 0; nf < 4; nf++) {
      unsigned int lo = (unsigned int)f2bf(s[nf][0]) | ((unsigned int)f2bf(s[nf][1]) << 16);
      unsigned int hi = (unsigned int)f2bf(s[nf][2]) | ((unsigned int)f2bf(s[nf][3]) << 16);
      int chunk = (nf * 2 + (lg >> 1)) ^ (ll & 7);
      uint2 pv; pv.x = lo; pv.y = hi;
      *(uint2*)((char*)&Plds[w][0] + ll * 128 + chunk * 16 + (lg & 1) * 8) = pv;
    }
    bf16x8 pb[2];
#pragma unroll
    for (int kk = 0; kk < 2; kk++) {
      int pc = (kk * 4 + lg) ^ (ll & 7);
      pb[kk] = *(const bf16x8*)((char*)&Plds[w][0] + ll * 128 + pc * 16);
    }
#pragma unroll
    for (int nf = 0; nf < 4; nf++) {
      int d = nf * 16 + ll;
#pragma unroll
      for (int kk = 0; kk < 2; kk++) {
        int vc = (kk * 4 + lg) ^ (d & 7);
        bf16x8 vb = *(const bf16x8*)((const char*)&Vt[buf][0] + d * 128 + vc * 16);
        oacc[nf] = __builtin_amdgcn_mfma_f32_16x16x32_bf16(vb, pb[kk], oacc[nf], 0, 0, 0);
      }
    }
    if (has_next) {
      unsigned int* vt32 = (unsigned int*)&Vt[buf ^ 1][0];
#pragma unroll
      for (int i = 0; i < 8; i++)
        vt32[(dg * 8 + i) * 32 + (((kp >> 2) ^ i) << 2) + (kp & 3)] =
            (unsigned int)n0.s[i] | ((unsigned int)n1.s[i] << 16);
    }
    __syncthreads();
    buf ^= 1;
  }

  float rl = 1.0f / lrun;
#pragma unroll
  for (int nf = 0; nf < 4; nf++) {
    ushort4 ov;
    ov.x = f2bf(oacc[nf][0] * rl);
    ov.y = f2bf(oacc[nf][1] * rl);
    ov.z = f2bf(oacc[nf][2] * rl);
    ov.w = f2bf(oacc[nf][3] * rl);
    *(ushort4*)(attn_o + (size_t)(b * SEQ + q_lane) * D_MODEL + h * 64 + nf * 16 + lg * 4) = ov;
  }
}

// ------------------------------------------------------------------------------
extern "C" void kernel_launch(void* const* d_in, const int* in_sizes, int n_in,
                              void* d_out, int out_size, void* d_ws, size_t ws_size,
                              hipStream_t stream) {
  const float* hidden_states = (const float*)d_in[0];
  const float* temb     = (const float*)d_in[2];
  const float* rope_cos = (const float*)d_in[3];
  const float* rope_sin = (const float*)d_in[4];
  const float* ln1_w    = (const float*)d_in[5];
  const float* ln1_b    = (const float*)d_in[6];
  const float* ln2_w    = (const float*)d_in[7];
  const float* ln2_b    = (const float*)d_in[8];
  const float* c_attn_w = (const float*)d_in[9];
  const float* c_attn_b = (const float*)d_in[10];
  const float* c_proj_w = (const float*)d_in[11];
  const float* c_proj_b = (const float*)d_in[12];
  const float* fc_w     = (const float*)d_in[13];
  const float* fc_b     = (const float*)d_in[14];
  const float* proj_w   = (const float*)d_in[15];
  const float* proj_b   = (const float*)d_in[16];
  const float* sst      = (const float*)d_in[17];

  char* ws = (char*)d_ws;
  unsigned short* wqkv  = (unsigned short*)(ws + 0);
  unsigned short* wproj = (unsigned short*)(ws + 6291456);
  unsigned short* wfc   = (unsigned short*)(ws + 8388608);
  unsigned short* wp2   = (unsigned short*)(ws + 16777216);
  unsigned short* hln   = (unsigned short*)(ws + 25165824);
  unsigned short* qkvb  = (unsigned short*)(ws + 33554432);
  unsigned short* attno = (unsigned short*)(ws + 58720256);
  unsigned short* h3    = (unsigned short*)(ws + 33554432);   // aliases qkvb+attno
  float*          hidden = (float*)(ws + 67108864);

  dim3 tb(32, 8);
  transpose_convert<<<dim3(3072 / 32, 1024 / 32), tb, 0, stream>>>(c_attn_w, wqkv, 1024, 3072);
  transpose_convert<<<dim3(1024 / 32, 1024 / 32), tb, 0, stream>>>(c_proj_w, wproj, 1024, 1024);
  transpose_convert<<<dim3(4096 / 32, 1024 / 32), tb, 0, stream>>>(fc_w, wfc, 1024, 4096);
  transpose_convert<<<dim3(1024 / 32, 4096 / 32), tb, 0, stream>>>(proj_w, wp2, 4096, 1024);

  ln_mod_kernel<0, 1><<<ROWS, 256, 0, stream>>>(hidden_states, ln1_w, ln1_b, sst, temb, hln);

  gemm_kernel<EPI_BF16, 4><<<dim3(3072 / 128, ROWS / 128), 256, 0, stream>>>(
      hln, wqkv, c_attn_b, qkvb, 3072, 1024, nullptr, nullptr, 0, nullptr);

  rope_kernel<<<(ROWS * 1024) / 256, 256, 0, stream>>>(qkvb, rope_cos, rope_sin);

  attn_kernel<<<dim3(32 * 32), 256, 0, stream>>>(qkvb, attno);

  gemm_kernel<EPI_RES, 2><<<dim3(1024 / 128, ROWS / 64), 256, 0, stream>>>(
      attno, wproj, c_proj_b, hidden, 1024, 1024, sst, temb, 2, hidden_states);

  ln_mod_kernel<3, 4><<<ROWS, 256, 0, stream>>>(hidden, ln2_w, ln2_b, sst, temb, hln);

  gemm_kernel<EPI_GELU, 4><<<dim3(4096 / 128, ROWS / 128), 256, 0, stream>>>(
      hln, wfc, fc_b, h3, 4096, 1024, nullptr, nullptr, 0, nullptr);

  gemm_kernel<EPI_FINAL, 2><<<dim3(1024 / 128, ROWS / 64), 256, 0, stream>>>(
      h3, wp2, proj_b, d_out, 1024, 4096, sst, temb, 5, hidden);
}